// Round 1
// baseline (24.935 us; speedup 1.0000x reference)
//
#include <hip/hip_runtime.h>

#define NPART 512
#define BATCH 128
#define NTHREADS 512

// One block handles half a batch's i-rows (256 rows, 2 threads per row).
// grid = BATCH * 2.
__global__ __launch_bounds__(NTHREADS, 2) void lj_partial(
    const float* __restrict__ x, float* __restrict__ partial) {
    const int bid = blockIdx.x;
    const int b = bid >> 1;
    const int s = bid & 1;
    const int tid = threadIdx.x;

    __shared__ float4 sp[NPART];   // xyz + pad -> ds_read_b128 per particle
    __shared__ float wred[8];
    __shared__ float wspr[8][4];

    const float* xb = x + (size_t)b * NPART * 3;
    // Stage 1536 floats coalesced into padded float4 LDS
    for (int idx = tid; idx < NPART * 3; idx += NTHREADS) {
        reinterpret_cast<float*>(sp)[(idx / 3) * 4 + (idx % 3)] = xb[idx];
    }
    __syncthreads();

    // row handled by this thread; half = which parity of k-offsets
    const int row = s * 256 + (tid >> 1);
    const int half = tid & 1;
    const float4 pi = sp[row];

    float acc6 = 0.0f, acc12 = 0.0f;
    #pragma unroll 8
    for (int k = 1 + half; k < NPART; k += 2) {
        const int j = (row + k) & (NPART - 1);
        const float4 pj = sp[j];
        const float dx = pi.x - pj.x;
        const float dy = pi.y - pj.y;
        const float dz = pi.z - pj.z;
        const float r2 = dx * dx + dy * dy + dz * dz;
        const float inv2 = __builtin_amdgcn_rcpf(r2);
        const float inv6 = inv2 * inv2 * inv2;
        acc12 = fmaf(inv6, inv6, acc12);
        acc6 += inv6;
    }
    float pot = acc12 - acc6;   // contribution: 4*(sum)/2 = 2*sum, scaled later

    // wave-level reduce (64 lanes)
    #pragma unroll
    for (int off = 32; off; off >>= 1) pot += __shfl_down(pot, off, 64);

    // spring partials: only split 0 computes them (has full batch in LDS)
    float sx = 0.0f, sy = 0.0f, sz = 0.0f, ssq = 0.0f;
    if (s == 0) {
        const float4 q = sp[tid];   // exactly one particle per thread
        sx = q.x; sy = q.y; sz = q.z;
        ssq = q.x * q.x + q.y * q.y + q.z * q.z;
        #pragma unroll
        for (int off = 32; off; off >>= 1) {
            sx  += __shfl_down(sx,  off, 64);
            sy  += __shfl_down(sy,  off, 64);
            sz  += __shfl_down(sz,  off, 64);
            ssq += __shfl_down(ssq, off, 64);
        }
    }

    const int wave = tid >> 6;
    const int lane = tid & 63;
    if (lane == 0) {
        wred[wave] = pot;
        wspr[wave][0] = sx; wspr[wave][1] = sy;
        wspr[wave][2] = sz; wspr[wave][3] = ssq;
    }
    __syncthreads();

    if (tid == 0) {
        float P = 0.0f, SX = 0.0f, SY = 0.0f, SZ = 0.0f, SS = 0.0f;
        #pragma unroll
        for (int w = 0; w < 8; ++w) {
            P += wred[w];
            SX += wspr[w][0]; SY += wspr[w][1];
            SZ += wspr[w][2]; SS += wspr[w][3];
        }
        float res = 2.0f * P;   // = 4*(acc12-acc6) summed over ordered pairs / 2
        if (s == 0) {
            // sum(rel^2) = ssq - N*com^2 ; restraint = 0.5*K*sum = 0.25*sum
            res += 0.25f * (SS - (SX * SX + SY * SY + SZ * SZ) * (1.0f / NPART));
        }
        partial[bid] = res;
    }
}

__global__ void lj_combine(const float* __restrict__ partial,
                           float* __restrict__ out) {
    const int t = blockIdx.x * blockDim.x + threadIdx.x;
    if (t < BATCH) {
        out[t] = -(partial[2 * t] + partial[2 * t + 1]);
    }
}

extern "C" void kernel_launch(void* const* d_in, const int* in_sizes, int n_in,
                              void* d_out, int out_size, void* d_ws, size_t ws_size,
                              hipStream_t stream) {
    const float* x = (const float*)d_in[0];
    float* out = (float*)d_out;
    float* pw = (float*)d_ws;   // 256 floats of partials

    lj_partial<<<BATCH * 2, NTHREADS, 0, stream>>>(x, pw);
    lj_combine<<<1, 128, 0, stream>>>(pw, out);
}

// Round 2
// 14.520 us; speedup vs baseline: 1.7173x; 1.7173x over previous
//
#include <hip/hip_runtime.h>

#define NPART 512
#define BATCH 128
#define SPLITS 8          // blocks per batch, each covers KR k-offsets
#define KR 32             // k-values per split: k in [1+KR*s, KR*(s+1)]
#define NTH 256           // threads per block; thread owns rows 2t, 2t+1

__device__ __forceinline__ void pair_term(const float4 a, const float4 b,
                                          float& acc12, float& acc6) {
    float dx = a.x - b.x, dy = a.y - b.y, dz = a.z - b.z;
    float r2 = fmaf(dx, dx, fmaf(dy, dy, dz * dz));
    float i2 = __builtin_amdgcn_rcpf(r2);
    float i6 = i2 * i2 * i2;
    acc12 = fmaf(i6, i6, acc12);
    acc6 += i6;
}

// grid = BATCH * SPLITS. Each unordered pair evaluated exactly once
// (cyclic-offset enumeration; k=256 terms corrected by 0.5 weight).
__global__ __launch_bounds__(NTH, 4) void lj_partial(
    const float* __restrict__ x, float* __restrict__ partial) {
    const int bid = blockIdx.x;
    const int b = bid >> 3;
    const int s = bid & 7;
    const int tid = threadIdx.x;

    __shared__ float4 sp[NPART + 256];   // mirrored: sp[512+p] = sp[p] for p<256
    __shared__ float wred[4];
    __shared__ float wspr[4][4];

    // Stage batch coords as padded float4 (xyz + pad), with mirror.
    const float* xb = x + (size_t)b * (NPART * 3);
    float* spf = reinterpret_cast<float*>(sp);
    #pragma unroll
    for (int t = 0; t < 6; ++t) {
        const int idx = tid + t * NTH;      // 0..1535
        const float v = xb[idx];
        const int p = idx / 3;
        const int c = idx - p * 3;
        spf[p * 4 + c] = v;
        if (p < 256) spf[(p + NPART) * 4 + c] = v;
    }
    __syncthreads();

    const int r0 = 2 * tid;
    const float4 pi0 = sp[r0];
    const float4 pi1 = sp[r0 + 1];
    const int k0 = 1 + KR * s;
    const float4* pj = &sp[r0 + k0];

    float acc6 = 0.0f, acc12 = 0.0f;

    // kk = 0: row0 only (pair (r0, r0+k0))
    {
        const float4 P = pj[0];
        pair_term(pi0, P, acc12, acc6);
    }
    // kk = 1..KR-1: P serves row0 (k=k0+kk) and row1 (k=k0+kk-1)
    #pragma unroll 8
    for (int kk = 1; kk < KR; ++kk) {
        const float4 P = pj[kk];
        pair_term(pi0, P, acc12, acc6);
        pair_term(pi1, P, acc12, acc6);
    }
    // kk = KR: row1 only (k = k0+KR-1)
    {
        const float4 P = pj[KR];
        pair_term(pi1, P, acc12, acc6);
    }

    // k=256 was counted at full weight by the last split for both rows;
    // each (i, i+256) pair appears twice globally -> net weight must be 1/2.
    if (s == SPLITS - 1) {
        {
            const float4 P = sp[r0 + 256];
            float dx = pi0.x - P.x, dy = pi0.y - P.y, dz = pi0.z - P.z;
            float r2 = fmaf(dx, dx, fmaf(dy, dy, dz * dz));
            float i2 = __builtin_amdgcn_rcpf(r2);
            float i6 = i2 * i2 * i2;
            acc12 -= 0.5f * i6 * i6;
            acc6 -= 0.5f * i6;
        }
        {
            const float4 P = sp[r0 + 1 + 256];
            float dx = pi1.x - P.x, dy = pi1.y - P.y, dz = pi1.z - P.z;
            float r2 = fmaf(dx, dx, fmaf(dy, dy, dz * dz));
            float i2 = __builtin_amdgcn_rcpf(r2);
            float i6 = i2 * i2 * i2;
            acc12 -= 0.5f * i6 * i6;
            acc6 -= 0.5f * i6;
        }
    }

    float pot = 4.0f * (acc12 - acc6);   // unordered pairs, each once

    #pragma unroll
    for (int off = 32; off; off >>= 1) pot += __shfl_down(pot, off, 64);

    // Harmonic COM restraint: only s==0 blocks (each thread owns 2 particles)
    float sx = 0.0f, sy = 0.0f, sz = 0.0f, ssq = 0.0f;
    if (s == 0) {
        sx = pi0.x + pi1.x;
        sy = pi0.y + pi1.y;
        sz = pi0.z + pi1.z;
        ssq = pi0.x * pi0.x + pi0.y * pi0.y + pi0.z * pi0.z
            + pi1.x * pi1.x + pi1.y * pi1.y + pi1.z * pi1.z;
        #pragma unroll
        for (int off = 32; off; off >>= 1) {
            sx  += __shfl_down(sx,  off, 64);
            sy  += __shfl_down(sy,  off, 64);
            sz  += __shfl_down(sz,  off, 64);
            ssq += __shfl_down(ssq, off, 64);
        }
    }

    const int wave = tid >> 6;
    const int lane = tid & 63;
    if (lane == 0) {
        wred[wave] = pot;
        wspr[wave][0] = sx; wspr[wave][1] = sy;
        wspr[wave][2] = sz; wspr[wave][3] = ssq;
    }
    __syncthreads();

    if (tid == 0) {
        float P = 0.0f, SX = 0.0f, SY = 0.0f, SZ = 0.0f, SS = 0.0f;
        #pragma unroll
        for (int w = 0; w < 4; ++w) {
            P += wred[w];
            SX += wspr[w][0]; SY += wspr[w][1];
            SZ += wspr[w][2]; SS += wspr[w][3];
        }
        float res = P;
        if (s == 0) {
            // 0.5*K*sum(rel^2), K=0.5 -> 0.25*(ssq - |sum|^2/N)
            res += 0.25f * (SS - (SX * SX + SY * SY + SZ * SZ) * (1.0f / NPART));
        }
        partial[bid] = res;
    }
}

__global__ void lj_combine(const float* __restrict__ partial,
                           float* __restrict__ out) {
    const int t = blockIdx.x * blockDim.x + threadIdx.x;
    if (t < BATCH) {
        float sum = 0.0f;
        #pragma unroll
        for (int i = 0; i < SPLITS; ++i) sum += partial[SPLITS * t + i];
        out[t] = -sum;
    }
}

extern "C" void kernel_launch(void* const* d_in, const int* in_sizes, int n_in,
                              void* d_out, int out_size, void* d_ws, size_t ws_size,
                              hipStream_t stream) {
    const float* x = (const float*)d_in[0];
    float* out = (float*)d_out;
    float* pw = (float*)d_ws;   // BATCH*SPLITS floats of partials

    lj_partial<<<BATCH * SPLITS, NTH, 0, stream>>>(x, pw);
    lj_combine<<<1, 128, 0, stream>>>(pw, out);
}